// Round 3
// baseline (366.907 us; speedup 1.0000x reference)
//
#include <hip/hip_runtime.h>
#include <math.h>

// DGPLoss on MI355X — R3: full-DRAM-row streaming.
// seg_feat: [B=4, C=64, H=512, W=512] f32, dep_true: [4,1,512,512] f32.
// loss = exp(-|dep_c - dep|/10 - sum_c(seg_c_cent - seg_c)^2), masked mean.
//
// Grid = (b, hp) = 408 blocks, 320 threads = 5 waves (wave = patch row).
// Lane covers 8 consecutive cols (2x float4) -> one wave reads a full
// contiguous 2 KB image row per channel iteration (= one DRAM row), fixing
// the 512 B @ 1 MB-stride pattern that capped R2 at ~38% HBM efficiency.

#define EPSF 1e-8f
#define PH 5
#define HPATCH 102
#define HH 512
#define WW 512
#define CC 64
#define HW (HH * WW)

__global__ __launch_bounds__(320) void dgp_main(const float* __restrict__ seg,
                                                const float* __restrict__ dep,
                                                float* __restrict__ ws) {
  const int bid = blockIdx.x;
  const int hp  = bid % HPATCH;
  const int b   = bid / HPATCH;
  const int h0  = hp * PH;
  const int hc  = h0 + 2;
  const int tid = threadIdx.x;
  const long seg_b = (long)b * CC * HW;

  __shared__ float s_cent[CC * 103];  // [c][wp], stride 103 -> bank=(7c+wp)%32
  __shared__ float s_depc[HPATCH];
  __shared__ float s_red[10];

  // ---- stage all 64x102 channel centers + 102 depth centers ----
  for (int idx = tid; idx < CC * HPATCH; idx += 320) {
    int c  = idx / HPATCH;
    int wp = idx - c * HPATCH;
    s_cent[c * 103 + wp] = seg[seg_b + (long)c * HW + (long)hc * WW + wp * PH + 2];
  }
  if (tid < HPATCH) {
    s_depc[tid] = dep[((long)b * HH + hc) * WW + tid * PH + 2];
  }
  __syncthreads();

  const int row  = tid >> 6;   // 0..4 within patch
  const int lane = tid & 63;
  const int col0 = lane * 8;   // 8 consecutive cols per lane
  const int h    = h0 + row;   // <= 509 always

  int wp[8];
#pragma unroll
  for (int j = 0; j < 8; ++j) wp[j] = (col0 + j) / PH;

  float acc[8] = {0.f, 0.f, 0.f, 0.f, 0.f, 0.f, 0.f, 0.f};
  const float* p = seg + seg_b + (long)h * WW + col0;

#pragma unroll 4
  for (int c = 0; c < CC; ++c) {
    float4 v0 = *(const float4*)(p + (long)c * HW);
    float4 v1 = *(const float4*)(p + (long)c * HW + 4);
    const float* cb = s_cent + c * 103;
    float vv[8] = {v0.x, v0.y, v0.z, v0.w, v1.x, v1.y, v1.z, v1.w};
#pragma unroll
    for (int j = 0; j < 8; ++j) {
      float d = cb[wp[j]] - vv[j];
      acc[j] = fmaf(d, d, acc[j]);
    }
  }

  // ---- depth branch + mask + loss for this thread's 8 pixels ----
  const float* dp = dep + ((long)b * HH + h) * WW + col0;
  float4 d0 = *(const float4*)dp;
  float4 d1 = *(const float4*)(dp + 4);
  float dv[8] = {d0.x, d0.y, d0.z, d0.w, d1.x, d1.y, d1.z, d1.w};

  float lsum = 0.f, lcnt = 0.f;
#pragma unroll
  for (int j = 0; j < 8; ++j) {
    int col = col0 + j;
    if (col < 510) {
      float dval = dv[j];
      float dd   = fabsf(s_depc[wp[j]] - dval);
      float ssq  = acc[j];
      bool is_center = (row == 2) && (col - wp[j] * PH == 2);
      bool m = (dd > EPSF) && (ssq > EPSF * EPSF) && (dval > EPSF) && !is_center;
      if (m) {
        lsum += __expf(-(dd * 0.1f + ssq));
        lcnt += 1.f;
      }
    }
  }

  // ---- reduce: wave64 shuffle, then across the 5 waves via LDS ----
#pragma unroll
  for (int off = 32; off > 0; off >>= 1) {
    lsum += __shfl_down(lsum, off, 64);
    lcnt += __shfl_down(lcnt, off, 64);
  }
  if (lane == 0) {
    s_red[row]     = lsum;
    s_red[5 + row] = lcnt;
  }
  __syncthreads();
  if (tid == 0) {
    float a = 0.f, n = 0.f;
#pragma unroll
    for (int w = 0; w < 5; ++w) {
      a += s_red[w];
      n += s_red[5 + w];
    }
    atomicAdd(&ws[0], a);
    atomicAdd(&ws[1], n);
  }
}

__global__ void dgp_final(const float* __restrict__ ws, float* __restrict__ out) {
  out[0] = ws[0] / fmaxf(ws[1], 1.0f);
}

extern "C" void kernel_launch(void* const* d_in, const int* in_sizes, int n_in,
                              void* d_out, int out_size, void* d_ws, size_t ws_size,
                              hipStream_t stream) {
  const float* seg = (const float*)d_in[0];
  const float* dep = (const float*)d_in[1];
  float* out = (float*)d_out;
  float* ws  = (float*)d_ws;

  hipMemsetAsync(d_ws, 0, 2 * sizeof(float), stream);

  const int nblocks = 4 * HPATCH;  // 408
  dgp_main<<<dim3(nblocks), dim3(320), 0, stream>>>(seg, dep, ws);
  dgp_final<<<1, 1, 0, stream>>>(ws, out);
}

// Round 4
// 362.825 us; speedup vs baseline: 1.0113x; 1.0113x over previous
//
#include <hip/hip_runtime.h>
#include <math.h>

// DGPLoss on MI355X — R4: non-temporal seg reads.
// seg_feat: [B=4, C=64, H=512, W=512] f32, dep_true: [4,1,512,512] f32.
// loss = exp(-|dep_c - dep|/10 - sum_c(seg_c_cent - seg_c)^2), masked mean.
//
// Theory: harness poisons 1 GB ws to 0xAA right before each replay -> LLC/L2
// full of dirty lines -> our 272 MB seg stream pays ~256 MB of forced dirty
// writebacks on its misses (structure-invariant ~110 us across R1/R2/R3).
// Fix: seg has zero reuse -> nt (no-allocate) loads skip the evictions.
// Structure = R2 (1632 blocks, 6.4/CU, float2 per lane).

#define EPSF 1e-8f
#define PH 5
#define HPATCH 102
#define HH 512
#define WW 512
#define CC 64
#define HW (HH * WW)

typedef float vf2 __attribute__((ext_vector_type(2)));

__global__ __launch_bounds__(320) void dgp_main(const float* __restrict__ seg,
                                                const float* __restrict__ dep,
                                                float* __restrict__ ws) {
  const int bid = blockIdx.x;
  const int q   = bid & 3;                  // col quarter (128 cols)
  const int hp  = (bid >> 2) % HPATCH;      // patch row
  const int b   = (bid >> 2) / HPATCH;      // batch
  const int h0  = hp * PH;
  const int hc  = h0 + 2;
  const int qbase = q * 128;

  // patches overlapping this quarter
  const int wp0   = qbase / PH;
  const int wpend = min((qbase + 127) / PH, HPATCH - 1);
  const int nwp   = wpend - wp0 + 1;        // 26 or 27

  __shared__ float s_cent[27 * 65];         // [wpl][c], stride 65 -> bank=(wpl+c)%32
  __shared__ float s_depc[27];
  __shared__ float s_red[10];

  const int tid = threadIdx.x;
  const long seg_b = (long)b * CC * HW;

  // ---- stage per-patch channel centers into LDS (div-free: 10 groups of 32) ----
  {
    const int grp = tid >> 5;               // 0..9 -> channel group
    const int wpl = tid & 31;               // 0..31 -> patch-local
    if (wpl < nwp) {
      const long base = seg_b + (long)hc * WW + (wp0 + wpl) * PH + 2;
      for (int c = grp; c < CC; c += 10) {
        s_cent[wpl * 65 + c] = __builtin_nontemporal_load(seg + base + (long)c * HW);
      }
    }
    if (tid < nwp) {
      s_depc[tid] = dep[((long)b * HH + hc) * WW + (wp0 + tid) * PH + 2];
    }
  }
  __syncthreads();

  const int row  = tid >> 6;                // 0..4 within patch
  const int lane = tid & 63;
  const int col0 = qbase + lane * 2;        // this thread's 2 cols

  int w0 = min(col0 / PH - wp0, nwp - 1);         // clamped; col>=510 masked later
  int w1 = min((col0 + 1) / PH - wp0, nwp - 1);

  const float* cb0 = s_cent + w0 * 65;
  const float* cb1 = s_cent + w1 * 65;

  float acc0 = 0.f, acc1 = 0.f;
  const float* p = seg + seg_b + (long)(h0 + row) * WW + col0;

#pragma unroll 8
  for (int c = 0; c < CC; ++c) {
    vf2 v = __builtin_nontemporal_load((const vf2*)(p + (long)c * HW));
    float d0 = cb0[c] - v.x;
    float d1 = cb1[c] - v.y;
    acc0 = fmaf(d0, d0, acc0);
    acc1 = fmaf(d1, d1, acc1);
  }

  // ---- depth branch + mask + loss for this thread's 2 pixels ----
  vf2 dv = __builtin_nontemporal_load((const vf2*)(dep + ((long)b * HH + h0 + row) * WW + col0));
  float dvals[2] = {dv.x, dv.y};
  float accs[2]  = {acc0, acc1};
  int wls[2]     = {w0, w1};

  float lsum = 0.f, lcnt = 0.f;
#pragma unroll
  for (int j = 0; j < 2; ++j) {
    int col = col0 + j;
    if (col < 510) {
      float dval = dvals[j];
      float dd   = fabsf(s_depc[wls[j]] - dval);
      float ssq  = accs[j];
      bool is_center = (row == 2) && (col % PH == 2);
      bool m = (dd > EPSF) && (ssq > EPSF * EPSF) && (dval > EPSF) && !is_center;
      if (m) {
        lsum += __expf(-(dd * 0.1f + ssq));
        lcnt += 1.f;
      }
    }
  }

  // ---- reduce: wave64 shuffle, then across the 5 waves via LDS ----
#pragma unroll
  for (int off = 32; off > 0; off >>= 1) {
    lsum += __shfl_down(lsum, off, 64);
    lcnt += __shfl_down(lcnt, off, 64);
  }
  if (lane == 0) {
    s_red[row]     = lsum;
    s_red[5 + row] = lcnt;
  }
  __syncthreads();
  if (tid == 0) {
    float a = 0.f, n = 0.f;
#pragma unroll
    for (int w = 0; w < 5; ++w) {
      a += s_red[w];
      n += s_red[5 + w];
    }
    atomicAdd(&ws[0], a);
    atomicAdd(&ws[1], n);
  }
}

__global__ void dgp_final(const float* __restrict__ ws, float* __restrict__ out) {
  out[0] = ws[0] / fmaxf(ws[1], 1.0f);
}

extern "C" void kernel_launch(void* const* d_in, const int* in_sizes, int n_in,
                              void* d_out, int out_size, void* d_ws, size_t ws_size,
                              hipStream_t stream) {
  const float* seg = (const float*)d_in[0];
  const float* dep = (const float*)d_in[1];
  float* out = (float*)d_out;
  float* ws  = (float*)d_ws;

  hipMemsetAsync(d_ws, 0, 2 * sizeof(float), stream);

  const int nblocks = 4 * HPATCH * 4;  // 1632
  dgp_main<<<dim3(nblocks), dim3(320), 0, stream>>>(seg, dep, ws);
  dgp_final<<<1, 1, 0, stream>>>(ws, out);
}